// Round 9
// baseline (111.668 us; speedup 1.0000x reference)
//
#include <hip/hip_runtime.h>

typedef _Float16 h2 __attribute__((ext_vector_type(2)));
typedef _Float16 h8 __attribute__((ext_vector_type(8)));
typedef __fp16   g2 __attribute__((ext_vector_type(2)));
typedef float    v4f __attribute__((ext_vector_type(4)));

namespace {
constexpr int BATCH = 4;
constexpr int IN_N  = 32;
constexpr int OUT_N = 32;
constexpr int H_IN  = 28;     // input spatial
constexpr int HW    = 26;     // output spatial (28-3+1)
constexpr int NI    = 288;    // IN_N * 3 * 3
constexpr int D     = 16;
constexpr int ITERS = 7;
constexpr float INV_SCALE = 1.0f / 3.0f;   // 1/(sqrt(16) * 0.75)
constexpr float EPS = 1e-5f;

constexpr int VH_S = 24;      // sVh row stride (halves, 48 B): b128 row reads conflict-free
constexpr int AT_S = 296;     // sAt row stride (halves, 592 B): 16B-aligned b128 rows
constexpr int P_S  = 36;      // step-5 partial stride (floats)

// DPP ctrl encodings
constexpr int DPP_XOR1 = 0xB1;   // quad_perm [1,0,3,2]
constexpr int DPP_XOR2 = 0x4E;   // quad_perm [2,3,0,1]
constexpr int DPP_HMIR = 0x141;  // row_half_mirror
constexpr int DPP_ROR4 = 0x124;  // row rotate 4 (within 16)
constexpr int DPP_ROR8 = 0x128;  // row rotate 8 == xor8 within 16
}

union H8U { h2 q[4]; h8 v; int2 i2[2]; };

static __device__ __forceinline__ int h2bits(h2 x) { union { h2 h; int i; } u; u.h = x; return u.i; }

// cvt_pkrtz returns __fp16x2; bit-cast to our _Float16-based h2
static __device__ __forceinline__ h2 pkrtz(float a, float b) {
  union { g2 g; h2 h; } u;
  u.g = __builtin_amdgcn_cvt_pkrtz(a, b);
  return u.h;
}

static __device__ __forceinline__ float dot2f(h2 a, h2 b, float c) {
#if __has_builtin(__builtin_amdgcn_fdot2)
  return __builtin_amdgcn_fdot2(a, b, c, false);
#else
  return c + (float)a.x * (float)b.x + (float)a.y * (float)b.y;
#endif
}

// x + dpp_perm(x): cross-lane add on the VALU pipe (no ds_bpermute)
template <int CTRL>
static __device__ __forceinline__ float dpp_add(float x) {
  union { float f; int i; } s, r;
  s.f = x;
  r.i = __builtin_amdgcn_update_dpp(s.i, s.i, CTRL, 0xF, 0xF, false);
  return x + r.f;
}

extern "C" __global__ __launch_bounds__(256, 4)
void capsule_fused(const float* __restrict__ input,
                   const float* __restrict__ w_current,
                   const float* __restrict__ w_next,
                   const float* __restrict__ ln_scale,
                   const float* __restrict__ ln_bias,
                   float* __restrict__ out) {
  // Manual LDS carving: 38144 B total -> 4 blocks/CU.
  __shared__ __align__(16) unsigned char smem[38144];
  _Float16* sVh  = (_Float16*)(smem);            // [288][24] halves (13824 B)
  float*    Pf   = (float*)(smem);               // overlay: step-5 partials [4][16][36] (9216 B)
  _Float16* sAt  = (_Float16*)(smem + 13824);    // A^T [32][296] halves (18944 B)
  float*    sQt  = (float*)(smem + 32768);       // qf^T [16][32] * INV_SCALE (2048 B)
  float*    sU   = (float*)(smem + 34816);       // u[0..287], v[288..319] (1280 B)
  float*    sScr = (float*)(smem + 36096);       // sinkhorn partial dbuf [2][128] / np (2048 B)

  const int t   = threadIdx.x;
  const int l   = t & 63;
  const int wv  = t >> 6;
  const int bid = blockIdx.x;
  const int b   = bid / (HW * HW);
  const int sp  = bid % (HW * HW);
  const int hh  = sp / HW;
  const int ww  = sp % HW;

  H8U zu; zu.i2[0] = make_int2(0, 0); zu.i2[1] = make_int2(0, 0);
  const h8 zero8 = zu.v;

  // stage qf^T scaled: sQt[d][o] = w_next[o][d] / 3
  for (int e = t; e < OUT_N * D; e += 256) {
    const int d = e >> 5, o = e & 31;
    sQt[d * 32 + o] = w_next[o * 16 + d] * INV_SCALE;
  }

  // ---- step 1: V[i][p*4+r] = sum_q pose[p][q]*w_current[q][r]; store f16 ----
  for (int i = t; i < NI; i += 256) {
    const int n = i / 9, kl = i % 9, ky = kl / 3, kx = kl % 3;
    const float* px = input + (((b * IN_N + n) * H_IN + (hh + ky)) * H_IN + (ww + kx)) * D;
    float p[16], wt[16];
    *(float4*)(p +  0) = *(const float4*)(px +  0);
    *(float4*)(p +  4) = *(const float4*)(px +  4);
    *(float4*)(p +  8) = *(const float4*)(px +  8);
    *(float4*)(p + 12) = *(const float4*)(px + 12);
    const float* wc = w_current + (kl * IN_N + n) * 16;
    *(float4*)(wt +  0) = *(const float4*)(wc +  0);
    *(float4*)(wt +  4) = *(const float4*)(wc +  4);
    *(float4*)(wt +  8) = *(const float4*)(wc +  8);
    *(float4*)(wt + 12) = *(const float4*)(wc + 12);
    float vv[16];
    #pragma unroll
    for (int pp = 0; pp < 4; ++pp)
      #pragma unroll
      for (int rr = 0; rr < 4; ++rr)
        vv[pp * 4 + rr] = p[pp*4+0]*wt[0+rr] + p[pp*4+1]*wt[4+rr]
                        + p[pp*4+2]*wt[8+rr] + p[pp*4+3]*wt[12+rr];
    H8U lo, hi;
    #pragma unroll
    for (int jj = 0; jj < 4; ++jj) {
      lo.q[jj] = pkrtz(vv[2*jj],     vv[2*jj + 1]);
      hi.q[jj] = pkrtz(vv[8 + 2*jj], vv[8 + 2*jj + 1]);
    }
    *(h8*)(sVh + i * VH_S)     = lo.v;
    *(h8*)(sVh + i * VH_S + 8) = hi.v;
  }
  __syncthreads();

  // ---- step 2: A^T[o][i] = exp(Vf[i].qf[o]/3) via MFMA 16x16x32 (K zero-padded) ----
  {
    const int lo16 = l & 15;
    const int q4   = l >> 4;          // k-quad
    const int kq   = (q4 & 1) * 8;    // real k base for quads 0,1
    const bool hiK = (q4 >= 2);       // quads 2,3 = zero-pad region (k>=16)
    h8 bf[2];
    #pragma unroll
    for (int nt = 0; nt < 2; ++nt) {
      const int o = lo16 + 16 * nt;
      H8U bu;
      #pragma unroll
      for (int jj = 0; jj < 4; ++jj)
        bu.q[jj] = pkrtz(sQt[(kq + 2*jj) * 32 + o], sQt[(kq + 2*jj + 1) * 32 + o]);
      bf[nt] = hiK ? zero8 : bu.v;
    }
    for (int mt = wv; mt < 18; mt += 4) {
      const int m = mt * 16 + lo16;
      h8 af = *(const h8*)(sVh + m * VH_S + kq);
      if (hiK) af = zero8;
      #pragma unroll
      for (int nt = 0; nt < 2; ++nt) {
        v4f acc = {0.f, 0.f, 0.f, 0.f};
        acc = __builtin_amdgcn_mfma_f32_16x16x32_f16(af, bf[nt], acc, 0, 0, 0);
        // D: col(o-within-tile)=l&15, row(i-offset)=4*q4+reg
        const int o  = lo16 + 16 * nt;
        const int ib = mt * 16 + 4 * q4;
        h2 p0 = pkrtz(__expf(acc[0]), __expf(acc[1]));
        h2 p1 = pkrtz(__expf(acc[2]), __expf(acc[3]));
        int2 wr; wr.x = h2bits(p0); wr.y = h2bits(p1);
        *(int2*)(sAt + o * AT_S + ib) = wr;   // A^T[o][ib..ib+3]
      }
    }
  }
  __syncthreads();

  // ---- step 3: Sinkhorn in registers, RESCALED (v-step = 8/colsum; exact x0.375 comp later).
  // ONE barrier per iteration: v lives in registers; col partials wave-folded via
  // DPP xor8 + shfl_xor(16/32), parity-double-buffered in sScr.
  const int c4 = t & 7;
  const int hq = t >> 3;
  h2 A2a[9], A2b[9];
  {
    const _Float16* r0 = sAt + (4*c4 + 0) * AT_S + 9 * hq;
    const _Float16* r1 = sAt + (4*c4 + 1) * AT_S + 9 * hq;
    const _Float16* r2 = sAt + (4*c4 + 2) * AT_S + 9 * hq;
    const _Float16* r3 = sAt + (4*c4 + 3) * AT_S + 9 * hq;
    #pragma unroll
    for (int j = 0; j < 9; ++j) {
      h2 a; a.x = r0[j]; a.y = r1[j]; A2a[j] = a;
      h2 c; c.x = r2[j]; c.y = r3[j]; A2b[j] = c;
    }
  }
  float ureg[9];
  float v0 = 1.f, v1 = 1.f, v2 = 1.f, v3 = 1.f;   // this thread's v for o=4c4..4c4+3
  h2 v2a = pkrtz(1.f, 1.f), v2b = v2a;
  for (int it = 0; it < ITERS; ++it) {
    // u-pass: row sums over o; reduce across the 8 c4-lanes via DPP (xor1,xor2,half-mirror)
    #pragma unroll
    for (int j = 0; j < 9; ++j) {
      float s = dot2f(A2b[j], v2b, dot2f(A2a[j], v2a, 0.f));
      s = dpp_add<DPP_XOR1>(s);
      s = dpp_add<DPP_XOR2>(s);
      s = dpp_add<DPP_HMIR>(s);
      ureg[j] = __builtin_amdgcn_rcpf(s);
    }
    // col-pass: packed f16 partial col sums over own 9 rows
    h2 aca; aca.x = (_Float16)0.f; aca.y = (_Float16)0.f;
    h2 acb = aca;
    #pragma unroll
    for (int j = 0; j < 9; ++j) {
      const h2 u2 = pkrtz(ureg[j], ureg[j]);
      aca += A2a[j] * u2;
      acb += A2b[j] * u2;
    }
    float sca = (float)aca.x, scb = (float)aca.y;
    float scc = (float)acb.x, scd = (float)acb.y;
    // fold the 8 hq-chunks of this wave: xor8 (DPP), xor16/xor32 (bpermute)
    sca = dpp_add<DPP_ROR8>(sca);
    scb = dpp_add<DPP_ROR8>(scb);
    scc = dpp_add<DPP_ROR8>(scc);
    scd = dpp_add<DPP_ROR8>(scd);
    sca += __shfl_xor(sca, 16); scb += __shfl_xor(scb, 16);
    scc += __shfl_xor(scc, 16); scd += __shfl_xor(scd, 16);
    sca += __shfl_xor(sca, 32); scb += __shfl_xor(scb, 32);
    scc += __shfl_xor(scc, 32); scd += __shfl_xor(scd, 32);
    float* buf = sScr + ((it & 1) << 7);
    if (l < 8) {
      v4f w4; w4[0] = sca; w4[1] = scb; w4[2] = scc; w4[3] = scd;
      *(v4f*)(buf + wv * 32 + l * 4) = w4;   // [wave][o]
    }
    __syncthreads();
    // every thread combines the 4 wave-partials for its own o-quad (broadcast reads)
    const v4f cw0 = *(const v4f*)(buf +       4 * c4);
    const v4f cw1 = *(const v4f*)(buf + 32  + 4 * c4);
    const v4f cw2 = *(const v4f*)(buf + 64  + 4 * c4);
    const v4f cw3 = *(const v4f*)(buf + 96  + 4 * c4);
    const v4f cs = cw0 + cw1 + cw2 + cw3;
    v0 = 8.0f * __builtin_amdgcn_rcpf(cs[0]);
    v1 = 8.0f * __builtin_amdgcn_rcpf(cs[1]);
    v2 = 8.0f * __builtin_amdgcn_rcpf(cs[2]);
    v3 = 8.0f * __builtin_amdgcn_rcpf(cs[3]);
    v2a = pkrtz(v0, v1);
    v2b = pkrtz(v2, v3);
  }
  // publish final u (c4==0 rows) and v (hq==0 threads) for steps 5/6
  if (c4 == 0) {
    #pragma unroll
    for (int j = 0; j < 9; ++j) sU[9 * hq + j] = ureg[j];
  }
  if (t < 8) {
    v4f vv4; vv4[0] = v0; vv4[1] = v1; vv4[2] = v2; vv4[3] = v3;
    *(v4f*)(sU + NI + 4 * t) = vv4;
  }
  __syncthreads();

  // ---- step 5: np~[o][d] = sum_k A^T[o][k] * (u_k * V[k][d]) via MFMA 16x16x32 ----
  v4f acc5_0 = {0.f, 0.f, 0.f, 0.f};
  v4f acc5_1 = {0.f, 0.f, 0.f, 0.f};
  {
    const int d  = l & 15;
    const int q4 = l >> 4;
    for (int kt = wv; kt < 9; kt += 4) {
      const int kg = kt * 32 + q4 * 8;
      const v4f ua = *(const v4f*)(sU + kg);
      const v4f ub = *(const v4f*)(sU + kg + 4);
      float uu[8];
      #pragma unroll
      for (int z = 0; z < 4; ++z) { uu[z] = ua[z]; uu[4 + z] = ub[z]; }
      H8U bu;
      #pragma unroll
      for (int jj = 0; jj < 4; ++jj) {
        const float b0 = (float)sVh[(kg + 2*jj)     * VH_S + d] * uu[2*jj];
        const float b1 = (float)sVh[(kg + 2*jj + 1) * VH_S + d] * uu[2*jj + 1];
        bu.q[jj] = pkrtz(b0, b1);
      }
      const h8 af0 = *(const h8*)(sAt + d * AT_S        + kt * 32 + q4 * 8);
      const h8 af1 = *(const h8*)(sAt + (16 + d) * AT_S + kt * 32 + q4 * 8);
      acc5_0 = __builtin_amdgcn_mfma_f32_16x16x32_f16(af0, bu.v, acc5_0, 0, 0, 0);
      acc5_1 = __builtin_amdgcn_mfma_f32_16x16x32_f16(af1, bu.v, acc5_1, 0, 0, 0);
    }
  }
  __syncthreads();   // all sVh/sAt reads done -> safe to overlay P into sVh
  {
    const int d = l & 15, q4 = l >> 4;
    // D: col=d, row(o-offset)=4*q4+reg
    *(v4f*)(Pf + (wv * 16 + d) * P_S + 0  + 4 * q4) = acc5_0;
    *(v4f*)(Pf + (wv * 16 + d) * P_S + 16 + 4 * q4) = acc5_1;
  }
  __syncthreads();
  // combine K-partials; np*3 = S~ * v~_o * (3/8)  (the /8 undoes the v rescale)
  #pragma unroll
  for (int pass = 0; pass < 2; ++pass) {
    const int e = t + 256 * pass;
    const int o = e & 31, dd = e >> 5;
    const float S = Pf[(0 * 16 + dd) * P_S + o] + Pf[(1 * 16 + dd) * P_S + o]
                  + Pf[(2 * 16 + dd) * P_S + o] + Pf[(3 * 16 + dd) * P_S + o];
    sScr[dd * 32 + o] = S * 0.375f * sU[NI + o];
  }
  __syncthreads();

  // ---- step 6: out[o][p*4+r] = sum_q np[o][p*4+q]*w_next[o][q*4+r]; LayerNorm over d ----
  {
    float vals[2];
    #pragma unroll
    for (int h2p = 0; h2p < 2; ++h2p) {
      const int e = t + h2p * 256;
      const int o = e >> 4, dd = e & 15;
      const int pp = dd >> 2, rr = dd & 3;
      float acc = 0.f;
      #pragma unroll
      for (int q = 0; q < 4; ++q)
        acc += sScr[(pp * 4 + q) * 32 + o] * sQt[(q * 4 + rr) * 32 + o];
      vals[h2p] = acc;
    }
    // LN over the 16 d's: full-16 DPP reduction (quad sums, then rotate-4/8)
    float s0 = vals[0], q0 = vals[0] * vals[0];
    float s1 = vals[1], q1 = vals[1] * vals[1];
    s0 = dpp_add<DPP_XOR1>(s0); q0 = dpp_add<DPP_XOR1>(q0);
    s1 = dpp_add<DPP_XOR1>(s1); q1 = dpp_add<DPP_XOR1>(q1);
    s0 = dpp_add<DPP_XOR2>(s0); q0 = dpp_add<DPP_XOR2>(q0);
    s1 = dpp_add<DPP_XOR2>(s1); q1 = dpp_add<DPP_XOR2>(q1);
    s0 = dpp_add<DPP_ROR4>(s0); q0 = dpp_add<DPP_ROR4>(q0);
    s1 = dpp_add<DPP_ROR4>(s1); q1 = dpp_add<DPP_ROR4>(q1);
    s0 = dpp_add<DPP_ROR8>(s0); q0 = dpp_add<DPP_ROR8>(q0);
    s1 = dpp_add<DPP_ROR8>(s1); q1 = dpp_add<DPP_ROR8>(q1);
    #pragma unroll
    for (int h2p = 0; h2p < 2; ++h2p) {
      const int e = t + h2p * 256;
      const int o = e >> 4, dd = e & 15;
      const float ss = h2p ? s1 : s0;
      const float qq = h2p ? q1 : q0;
      const float mu   = ss * (1.0f / 16.0f);
      const float var  = qq * (1.0f / 16.0f) - mu * mu;
      const float rstd = rsqrtf(var + EPS);
      const float y = (vals[h2p] - mu) * rstd * ln_scale[dd] + ln_bias[dd];
      out[(((b * OUT_N + o) * HW + hh) * HW + ww) * D + dd] = y;
    }
  }
}

extern "C" void kernel_launch(void* const* d_in, const int* in_sizes, int n_in,
                              void* d_out, int out_size, void* d_ws, size_t ws_size,
                              hipStream_t stream) {
  const float* input     = (const float*)d_in[0];
  const float* w_current = (const float*)d_in[1];
  const float* w_next    = (const float*)d_in[2];
  const float* ln_scale  = (const float*)d_in[3];
  const float* ln_bias   = (const float*)d_in[4];
  float* outp = (float*)d_out;

  dim3 grid(BATCH * HW * HW);   // 2704 blocks, one per (b, h, w)
  dim3 block(256);
  capsule_fused<<<grid, block, 0, stream>>>(input, w_current, w_next,
                                            ln_scale, ln_bias, outp);
}

// Round 10
// 108.864 us; speedup vs baseline: 1.0258x; 1.0258x over previous
//
#include <hip/hip_runtime.h>

typedef _Float16 h2 __attribute__((ext_vector_type(2)));
typedef _Float16 h8 __attribute__((ext_vector_type(8)));
typedef __fp16   g2 __attribute__((ext_vector_type(2)));
typedef float    v4f __attribute__((ext_vector_type(4)));

namespace {
constexpr int BATCH = 4;
constexpr int IN_N  = 32;
constexpr int OUT_N = 32;
constexpr int H_IN  = 28;     // input spatial
constexpr int HW    = 26;     // output spatial (28-3+1)
constexpr int NI    = 288;    // IN_N * 3 * 3
constexpr int D     = 16;
constexpr int ITERS = 7;
constexpr float INV_SCALE = 1.0f / 3.0f;   // 1/(sqrt(16) * 0.75)
constexpr float EPS = 1e-5f;

constexpr int VH_S = 16;      // sVh row stride (halves, 32 B) -- tight for 5 blocks/CU
constexpr int AT_S = 288;     // sAt row stride (halves, 576 B): 16B-aligned b128 rows
constexpr int P_S  = 36;      // step-5 partial stride (floats); [4][16][36]*4B = 9216 B = sVh size

// DPP ctrl encodings
constexpr int DPP_XOR1 = 0xB1;   // quad_perm [1,0,3,2]
constexpr int DPP_XOR2 = 0x4E;   // quad_perm [2,3,0,1]
constexpr int DPP_HMIR = 0x141;  // row_half_mirror
constexpr int DPP_ROR4 = 0x124;  // row rotate 4 (within 16)
constexpr int DPP_ROR8 = 0x128;  // row rotate 8 == xor8 within 16
}

union H8U { h2 q[4]; h8 v; int2 i2[2]; };

static __device__ __forceinline__ int h2bits(h2 x) { union { h2 h; int i; } u; u.h = x; return u.i; }

// cvt_pkrtz returns __fp16x2; bit-cast to our _Float16-based h2
static __device__ __forceinline__ h2 pkrtz(float a, float b) {
  union { g2 g; h2 h; } u;
  u.g = __builtin_amdgcn_cvt_pkrtz(a, b);
  return u.h;
}

static __device__ __forceinline__ float dot2f(h2 a, h2 b, float c) {
#if __has_builtin(__builtin_amdgcn_fdot2)
  return __builtin_amdgcn_fdot2(a, b, c, false);
#else
  return c + (float)a.x * (float)b.x + (float)a.y * (float)b.y;
#endif
}

// x + dpp_perm(x): cross-lane add on the VALU pipe (no ds_bpermute)
template <int CTRL>
static __device__ __forceinline__ float dpp_add(float x) {
  union { float f; int i; } s, r;
  s.f = x;
  r.i = __builtin_amdgcn_update_dpp(s.i, s.i, CTRL, 0xF, 0xF, false);
  return x + r.f;
}

extern "C" __global__ __launch_bounds__(256, 5)
void capsule_fused(const float* __restrict__ input,
                   const float* __restrict__ w_current,
                   const float* __restrict__ w_next,
                   const float* __restrict__ ln_scale,
                   const float* __restrict__ ln_bias,
                   float* __restrict__ out) {
  // Manual LDS carving: 32512 B total -> 5 blocks/CU (160 KiB / 32.5 KB).
  __shared__ __align__(16) unsigned char smem[32512];
  _Float16* sVh  = (_Float16*)(smem);            // [288][16] halves (9216 B)
  float*    Pf   = (float*)(smem);               // overlay: step-5 partials [4][16][36] (9216 B)
  _Float16* sAt  = (_Float16*)(smem + 9216);     // A^T [32][288] halves (18432 B)
  float*    sQt  = (float*)(smem + 27648);       // qf^T [16][32] * INV_SCALE (2048 B)
  _Float16* sUh  = (_Float16*)(smem + 29696);    // u[0..287] f16 (576 B, pad to 640)
  float*    sVv  = (float*)(smem + 30336);       // v[0..31] f32 (128 B)
  float*    sScr = (float*)(smem + 30464);       // sinkhorn col partials [16][32] / np (2048 B)

  const int t   = threadIdx.x;
  const int l   = t & 63;
  const int wv  = t >> 6;
  const int bid = blockIdx.x;
  const int b   = bid / (HW * HW);
  const int sp  = bid % (HW * HW);
  const int hh  = sp / HW;
  const int ww  = sp % HW;

  H8U zu; zu.i2[0] = make_int2(0, 0); zu.i2[1] = make_int2(0, 0);
  const h8 zero8 = zu.v;

  // stage qf^T scaled: sQt[d][o] = w_next[o][d] / 3
  for (int e = t; e < OUT_N * D; e += 256) {
    const int d = e >> 5, o = e & 31;
    sQt[d * 32 + o] = w_next[o * 16 + d] * INV_SCALE;
  }
  if (t < 32) sVv[t] = 1.0f;   // v init

  // ---- step 1: V[i][p*4+r] = sum_q pose[p][q]*w_current[q][r]; store f16 ----
  for (int i = t; i < NI; i += 256) {
    const int n = i / 9, kl = i % 9, ky = kl / 3, kx = kl % 3;
    const float* px = input + (((b * IN_N + n) * H_IN + (hh + ky)) * H_IN + (ww + kx)) * D;
    float p[16], wt[16];
    *(float4*)(p +  0) = *(const float4*)(px +  0);
    *(float4*)(p +  4) = *(const float4*)(px +  4);
    *(float4*)(p +  8) = *(const float4*)(px +  8);
    *(float4*)(p + 12) = *(const float4*)(px + 12);
    const float* wc = w_current + (kl * IN_N + n) * 16;
    *(float4*)(wt +  0) = *(const float4*)(wc +  0);
    *(float4*)(wt +  4) = *(const float4*)(wc +  4);
    *(float4*)(wt +  8) = *(const float4*)(wc +  8);
    *(float4*)(wt + 12) = *(const float4*)(wc + 12);
    float vv[16];
    #pragma unroll
    for (int pp = 0; pp < 4; ++pp)
      #pragma unroll
      for (int rr = 0; rr < 4; ++rr)
        vv[pp * 4 + rr] = p[pp*4+0]*wt[0+rr] + p[pp*4+1]*wt[4+rr]
                        + p[pp*4+2]*wt[8+rr] + p[pp*4+3]*wt[12+rr];
    H8U lo, hi;
    #pragma unroll
    for (int jj = 0; jj < 4; ++jj) {
      lo.q[jj] = pkrtz(vv[2*jj],     vv[2*jj + 1]);
      hi.q[jj] = pkrtz(vv[8 + 2*jj], vv[8 + 2*jj + 1]);
    }
    *(h8*)(sVh + i * VH_S)     = lo.v;
    *(h8*)(sVh + i * VH_S + 8) = hi.v;
  }
  __syncthreads();

  // ---- step 2: A^T[o][i] = exp(Vf[i].qf[o]/3) via MFMA 16x16x32 (K zero-padded) ----
  {
    const int lo16 = l & 15;
    const int q4   = l >> 4;          // k-quad
    const int kq   = (q4 & 1) * 8;    // real k base for quads 0,1
    const bool hiK = (q4 >= 2);       // quads 2,3 = zero-pad region (k>=16)
    h8 bf[2];
    #pragma unroll
    for (int nt = 0; nt < 2; ++nt) {
      const int o = lo16 + 16 * nt;
      H8U bu;
      #pragma unroll
      for (int jj = 0; jj < 4; ++jj)
        bu.q[jj] = pkrtz(sQt[(kq + 2*jj) * 32 + o], sQt[(kq + 2*jj + 1) * 32 + o]);
      bf[nt] = hiK ? zero8 : bu.v;
    }
    for (int mt = wv; mt < 18; mt += 4) {
      const int m = mt * 16 + lo16;
      h8 af = *(const h8*)(sVh + m * VH_S + kq);
      if (hiK) af = zero8;
      #pragma unroll
      for (int nt = 0; nt < 2; ++nt) {
        v4f acc = {0.f, 0.f, 0.f, 0.f};
        acc = __builtin_amdgcn_mfma_f32_16x16x32_f16(af, bf[nt], acc, 0, 0, 0);
        // D: col(o-within-tile)=l&15, row(i-offset)=4*q4+reg
        const int o  = lo16 + 16 * nt;
        const int ib = mt * 16 + 4 * q4;
        h2 p0 = pkrtz(__expf(acc[0]), __expf(acc[1]));
        h2 p1 = pkrtz(__expf(acc[2]), __expf(acc[3]));
        int2 wr; wr.x = h2bits(p0); wr.y = h2bits(p1);
        *(int2*)(sAt + o * AT_S + ib) = wr;   // A^T[o][ib..ib+3]
      }
    }
  }
  __syncthreads();

  // ---- step 3: Sinkhorn in registers, RESCALED (v-step = 8/colsum; exact x0.375 comp later).
  // R7 structure (measured best): DPP reductions, f32 col partials, 2 barriers/iter.
  const int c4 = t & 7;
  const int hq = t >> 3;
  h2 A2a[9], A2b[9];
  {
    const _Float16* r0 = sAt + (4*c4 + 0) * AT_S + 9 * hq;
    const _Float16* r1 = sAt + (4*c4 + 1) * AT_S + 9 * hq;
    const _Float16* r2 = sAt + (4*c4 + 2) * AT_S + 9 * hq;
    const _Float16* r3 = sAt + (4*c4 + 3) * AT_S + 9 * hq;
    #pragma unroll
    for (int j = 0; j < 9; ++j) {
      h2 a; a.x = r0[j]; a.y = r1[j]; A2a[j] = a;
      h2 c; c.x = r2[j]; c.y = r3[j]; A2b[j] = c;
    }
  }
  float ureg[9];
  for (int it = 0; it < ITERS; ++it) {
    const v4f vvv = *(const v4f*)(sVv + 4 * c4);
    const h2 v2a = pkrtz(vvv[0], vvv[1]);
    const h2 v2b = pkrtz(vvv[2], vvv[3]);
    // u-pass: row sums over o; reduce across the 8 c4-lanes via DPP (xor1,xor2,half-mirror)
    #pragma unroll
    for (int j = 0; j < 9; ++j) {
      float s = dot2f(A2b[j], v2b, dot2f(A2a[j], v2a, 0.f));
      s = dpp_add<DPP_XOR1>(s);
      s = dpp_add<DPP_XOR2>(s);
      s = dpp_add<DPP_HMIR>(s);
      ureg[j] = __builtin_amdgcn_rcpf(s);
    }
    // col-pass: fp32 partial col sums; ror:8 folds the two hq-chunks in each 16-row
    float sca = 0.f, scb = 0.f, scc = 0.f, scd = 0.f;
    #pragma unroll
    for (int j = 0; j < 9; ++j) {
      const float uj = ureg[j];
      sca += (float)A2a[j].x * uj;
      scb += (float)A2a[j].y * uj;
      scc += (float)A2b[j].x * uj;
      scd += (float)A2b[j].y * uj;
    }
    sca = dpp_add<DPP_ROR8>(sca);
    scb = dpp_add<DPP_ROR8>(scb);
    scc = dpp_add<DPP_ROR8>(scc);
    scd = dpp_add<DPP_ROR8>(scd);
    if ((l & 15) < 8) {
      v4f w4; w4[0] = sca; w4[1] = scb; w4[2] = scc; w4[3] = scd;
      *(v4f*)(sScr + (t >> 4) * 32 + (l & 7) * 4) = w4;   // [16-group][o]
    }
    __syncthreads();
    if (t < 32) {
      float S = 0.f;
      #pragma unroll
      for (int g = 0; g < 16; ++g) S += sScr[g * 32 + t];
      sVv[t] = 8.0f * __builtin_amdgcn_rcpf(S);   // rescaled v
    }
    __syncthreads();
  }
  if (c4 == 0) {
    #pragma unroll
    for (int j = 0; j < 9; ++j) sUh[9 * hq + j] = (_Float16)ureg[j];
  }
  __syncthreads();

  // ---- step 5: np~[o][d] = sum_k A^T[o][k] * (u_k * V[k][d]) via MFMA 16x16x32 ----
  v4f acc5_0 = {0.f, 0.f, 0.f, 0.f};
  v4f acc5_1 = {0.f, 0.f, 0.f, 0.f};
  {
    const int d  = l & 15;
    const int q4 = l >> 4;
    for (int kt = wv; kt < 9; kt += 4) {
      const int kg = kt * 32 + q4 * 8;
      H8U uh; uh.v = *(const h8*)(sUh + kg);     // u[kg..kg+7] f16, one b128
      H8U bu;
      #pragma unroll
      for (int jj = 0; jj < 4; ++jj) {
        h2 vh;
        vh.x = sVh[(kg + 2*jj)     * VH_S + d];
        vh.y = sVh[(kg + 2*jj + 1) * VH_S + d];
        bu.q[jj] = vh * uh.q[jj];                // packed f16 mul
      }
      const h8 af0 = *(const h8*)(sAt + d * AT_S        + kg);
      const h8 af1 = *(const h8*)(sAt + (16 + d) * AT_S + kg);
      acc5_0 = __builtin_amdgcn_mfma_f32_16x16x32_f16(af0, bu.v, acc5_0, 0, 0, 0);
      acc5_1 = __builtin_amdgcn_mfma_f32_16x16x32_f16(af1, bu.v, acc5_1, 0, 0, 0);
    }
  }
  __syncthreads();   // all sVh/sAt reads done -> safe to overlay P into sVh
  {
    const int d = l & 15, q4 = l >> 4;
    // D: col=d, row(o-offset)=4*q4+reg
    *(v4f*)(Pf + (wv * 16 + d) * P_S + 0  + 4 * q4) = acc5_0;
    *(v4f*)(Pf + (wv * 16 + d) * P_S + 16 + 4 * q4) = acc5_1;
  }
  __syncthreads();
  // combine K-partials; np*3 = S~ * v~_o * (3/8)  (the /8 undoes the v rescale)
  #pragma unroll
  for (int pass = 0; pass < 2; ++pass) {
    const int e = t + 256 * pass;
    const int o = e & 31, dd = e >> 5;
    const float S = Pf[(0 * 16 + dd) * P_S + o] + Pf[(1 * 16 + dd) * P_S + o]
                  + Pf[(2 * 16 + dd) * P_S + o] + Pf[(3 * 16 + dd) * P_S + o];
    sScr[dd * 32 + o] = S * 0.375f * sVv[o];
  }
  __syncthreads();

  // ---- step 6: out[o][p*4+r] = sum_q np[o][p*4+q]*w_next[o][q*4+r]; LayerNorm over d ----
  {
    float vals[2];
    #pragma unroll
    for (int h2p = 0; h2p < 2; ++h2p) {
      const int e = t + h2p * 256;
      const int o = e >> 4, dd = e & 15;
      const int pp = dd >> 2, rr = dd & 3;
      float acc = 0.f;
      #pragma unroll
      for (int q = 0; q < 4; ++q)
        acc += sScr[(pp * 4 + q) * 32 + o] * sQt[(q * 4 + rr) * 32 + o];
      vals[h2p] = acc;
    }
    // LN over the 16 d's: full-16 DPP reduction (quad sums, then rotate-4/8)
    float s0 = vals[0], q0 = vals[0] * vals[0];
    float s1 = vals[1], q1 = vals[1] * vals[1];
    s0 = dpp_add<DPP_XOR1>(s0); q0 = dpp_add<DPP_XOR1>(q0);
    s1 = dpp_add<DPP_XOR1>(s1); q1 = dpp_add<DPP_XOR1>(q1);
    s0 = dpp_add<DPP_XOR2>(s0); q0 = dpp_add<DPP_XOR2>(q0);
    s1 = dpp_add<DPP_XOR2>(s1); q1 = dpp_add<DPP_XOR2>(q1);
    s0 = dpp_add<DPP_ROR4>(s0); q0 = dpp_add<DPP_ROR4>(q0);
    s1 = dpp_add<DPP_ROR4>(s1); q1 = dpp_add<DPP_ROR4>(q1);
    s0 = dpp_add<DPP_ROR8>(s0); q0 = dpp_add<DPP_ROR8>(q0);
    s1 = dpp_add<DPP_ROR8>(s1); q1 = dpp_add<DPP_ROR8>(q1);
    #pragma unroll
    for (int h2p = 0; h2p < 2; ++h2p) {
      const int e = t + h2p * 256;
      const int o = e >> 4, dd = e & 15;
      const float ss = h2p ? s1 : s0;
      const float qq = h2p ? q1 : q0;
      const float mu   = ss * (1.0f / 16.0f);
      const float var  = qq * (1.0f / 16.0f) - mu * mu;
      const float rstd = rsqrtf(var + EPS);
      const float y = (vals[h2p] - mu) * rstd * ln_scale[dd] + ln_bias[dd];
      out[(((b * OUT_N + o) * HW + hh) * HW + ww) * D + dd] = y;
    }
  }
}

extern "C" void kernel_launch(void* const* d_in, const int* in_sizes, int n_in,
                              void* d_out, int out_size, void* d_ws, size_t ws_size,
                              hipStream_t stream) {
  const float* input     = (const float*)d_in[0];
  const float* w_current = (const float*)d_in[1];
  const float* w_next    = (const float*)d_in[2];
  const float* ln_scale  = (const float*)d_in[3];
  const float* ln_bias   = (const float*)d_in[4];
  float* outp = (float*)d_out;

  dim3 grid(BATCH * HW * HW);   // 2704 blocks, one per (b, h, w)
  dim3 block(256);
  capsule_fused<<<grid, block, 0, stream>>>(input, w_current, w_next,
                                            ln_scale, ln_bias, outp);
}